// Round 11
// baseline (3555.378 us; speedup 1.0000x reference)
//
#include <hip/hip_runtime.h>
#include <math.h>

#define E 180
#define S 112
#define Bb 256
#define CC 14
#define TT 8
#define HH 5
#define DH 36
#define NBLK 6
#define MLPD 720
#define M_TOK (Bb*S)              // 28672
#define BUF ((size_t)M_TOK * E)   // 5,160,960 elements

#define KP1 192                   // padded K for E=180 (6x32)
#define KP2 736                   // padded K for 720 (23x32)

// W8 arena per-block element offsets
#define WQ8_OFF   0
#define WK8_OFF   36864
#define WV8_OFF   73728
#define WO8_OFF   110592
#define FC18_OFF  147456
#define FC28_OFF  285696
#define WBLK      427008

// amax slot indices (each slot = double bits in unsigned long long)
#define SLOT_X    0
#define SLOT_PW   1
#define SLOT_CW   2
#define SLOT_POOL 3
#define SLOT_FLN  4
#define SLOT_WQ   8
#define SLOT_WK   16
#define SLOT_WV   24
#define SLOT_WO   32
#define SLOT_FC1  40
#define SLOT_FC2  48
#define SLOT_LN1  56
#define SLOT_O    64
#define SLOT_LN2  72
#define SLOT_GELU 80
// gelu-amax candidate slots (per transformer block)
#define SLOT_GXMAX 88
#define SLOT_GXA   96
#define SLOT_GXB   104
#define SLOT_GDIR  112

#define XL (-0.7535)
#define XR (-0.7515)

typedef unsigned long long ull;
typedef __attribute__((ext_vector_type(8))) short short8;
typedef __attribute__((ext_vector_type(4))) float f32x4;

__device__ __forceinline__ double slot_scale(const ull* s){
  return fmax(__longlong_as_double((long long)*s) / 127.0, 1e-8);
}
__device__ __forceinline__ void atomic_max_d(ull* p, double v){
  atomicMax(p, (ull)__double_as_longlong(v));   // v >= 0 -> bit-monotone
}
__device__ __forceinline__ ull enc_d(double d){
  ull b = (ull)__double_as_longlong(d);
  return (b >> 63) ? ~b : (b | 0x8000000000000000ULL);
}
__device__ __forceinline__ double dec_d(ull k){
  ull b = (k >> 63) ? (k ^ 0x8000000000000000ULL) : ~k;
  return __longlong_as_double((long long)b);
}
__device__ __forceinline__ float q_int_d(double x, double s){
  double r = rint(x / s);
  r = fmin(fmax(r, -128.0), 127.0);
  return (float)r;
}
__device__ __forceinline__ float q_int_fast(double x, double s, float sf){
  float t = (float)x / sf;
  float r = rintf(t);
  if(fabsf(t - r) > 0.497f || fabsf(t) > 126.f){
    double rd = rint(x / s);
    rd = fmin(fmax(rd, -128.0), 127.0);
    return (float)rd;
  }
  return r;
}
__device__ __forceinline__ unsigned short f2bf(float f){
  return (unsigned short)(__float_as_uint(f) >> 16);
}
__device__ __forceinline__ double gelu_d(double x){
  double t = tanh(0.7978845608028654*(x + 0.044715*x*x*x));
  return 0.5*x*(1.0 + t);
}
__device__ __forceinline__ float gelu_f(float x){
  float t = tanhf(0.7978845608f*(x + 0.044715f*x*x*x));
  return 0.5f*x*(1.f + t);
}
__device__ __forceinline__ int pmap(int row, int mode){
  if(mode == 0) return row;
  int b = row / S; int r = row - b*S; int t = r / CC; int c = r - t*CC;
  return b*S + c*TT + t;
}
__device__ __forceinline__ int pmap_inv(int row){
  int b = row / S; int r = row - b*S; int c = r / TT; int t = r - c*TT;
  return b*S + t*CC + c;
}

__global__ void init_slots(ull* slots){
  int t = threadIdx.x;
  slots[t] = (t >= SLOT_GXB && t < SLOT_GXB + NBLK) ? ~0ULL : 0ULL;
}

// zero the pad columns (720..735) of mid8 once
__global__ void zero_pad(unsigned short* __restrict__ mid8){
  int tid = blockIdx.x*256 + threadIdx.x;
  if(tid >= M_TOK*2) return;
  int row = tid >> 1, half = tid & 1;
  short8 z = (short8){0,0,0,0,0,0,0,0};
  *reinterpret_cast<short8*>(mid8 + (size_t)row*KP2 + MLPD + half*8) = z;
}

__global__ void amax_f32(const float* __restrict__ src, int seglen, ull* slots){
  int seg = blockIdx.y;
  const float* p = src + (size_t)seg * seglen;
  float m = 0.f;
  for(int i = blockIdx.x*256 + threadIdx.x; i < seglen; i += gridDim.x*256)
    m = fmaxf(m, fabsf(p[i]));
  __shared__ float red[256];
  red[threadIdx.x] = m;
  __syncthreads();
  for(int off = 128; off > 0; off >>= 1){
    if(threadIdx.x < off) red[threadIdx.x] = fmaxf(red[threadIdx.x], red[threadIdx.x+off]);
    __syncthreads();
  }
  if(threadIdx.x == 0) atomic_max_d(slots + seg, (double)red[0]);
}

__global__ void quant_w(const float* __restrict__ src, int N, int K,
                        int Npad, int Kpad, const ull* __restrict__ slotbase,
                        unsigned short* __restrict__ dst, size_t dstoff){
  int i = blockIdx.y;
  int e = blockIdx.x*256 + threadIdx.x;
  int tot = Npad * Kpad;
  if(e >= tot) return;
  int n = e / Kpad, k = e - n*Kpad;
  double s = slot_scale(slotbase + i);
  float val = 0.f;
  if(n < N && k < K)
    val = q_int_d((double)src[(size_t)i*N*K + (size_t)n*K + k], s);
  dst[(size_t)i*WBLK + dstoff + e] = f2bf(val);
}

__global__ void proj_bcast(const float* __restrict__ x, const float* __restrict__ pw,
                           const float* __restrict__ pb, double* __restrict__ h,
                           const ull* __restrict__ sx_slot,
                           const ull* __restrict__ sw_slot){
  int tid = blockIdx.x*256 + threadIdx.x;
  if(tid >= Bb*TT*E) return;
  int e = tid % E; int bt = tid / E; int t = bt % TT; int b = bt / TT;
  double sx = slot_scale(sx_slot), sw = slot_scale(sw_slot);
  float acc = 0.f;
  for(int c = 0; c < CC; c++)
    acc += q_int_d((double)x[(b*CC + c)*TT + t], sx) * q_int_d((double)pw[e*CC + c], sw);
  double o = (double)acc * (sx * sw) + (double)pb[e];
  for(int c = 0; c < CC; c++)
    h[((size_t)b*S + c*TT + t)*E + e] = o;
}

// shared LN row computation (bit-identical between passes that use it)
__device__ __forceinline__ void ln_row(const double* __restrict__ in, size_t base, int lane,
    const float* __restrict__ g, const float* __restrict__ bta,
    double& y0, double& y1, double& y2){
  double x0 = in[base + lane];
  double x1 = in[base + lane + 64];
  double x2 = (lane < E - 128) ? in[base + lane + 128] : 0.0;
  double sum = x0 + x1 + x2;
  for(int m = 32; m > 0; m >>= 1) sum += __shfl_xor(sum, m);
  double mean = sum * (1.0 / E);
  double d0 = x0 - mean, d1 = x1 - mean;
  double d2 = (lane < E - 128) ? (x2 - mean) : 0.0;
  double vs = d0*d0 + d1*d1 + d2*d2;
  for(int m = 32; m > 0; m >>= 1) vs += __shfl_xor(vs, m);
  double inv = 1.0 / sqrt(vs * (1.0 / E) + 1e-5);
  y0 = d0*inv*(double)g[lane]      + (double)bta[lane];
  y1 = d1*inv*(double)g[lane+64]   + (double)bta[lane+64];
  y2 = (lane < E - 128) ? (d2*inv*(double)g[lane+128] + (double)bta[lane+128]) : 0.0;
}

template<bool WRITE>
__global__ void __launch_bounds__(256) ln_amax(const double* __restrict__ in,
    double* __restrict__ out, const float* __restrict__ g,
    const float* __restrict__ bta, ull* amax_slot){
  int wave = threadIdx.x >> 6, lane = threadIdx.x & 63;
  double amx = 0.0;
  for(int tok = blockIdx.x*4 + wave; tok < M_TOK; tok += gridDim.x*4){
    size_t base = (size_t)tok * E;
    double y0, y1, y2;
    ln_row(in, base, lane, g, bta, y0, y1, y2);
    if(WRITE){
      out[base + lane]      = y0;
      out[base + lane + 64] = y1;
      if(lane < E - 128) out[base + lane + 128] = y2;
    }
    amx = fmax(amx, fmax(fabs(y0), fabs(y1)));
    if(lane < E - 128) amx = fmax(amx, fabs(y2));
  }
  for(int m = 32; m > 0; m >>= 1) amx = fmax(amx, __shfl_xor(amx, m));
  __shared__ double red[4];
  if(lane == 0) red[wave] = amx;
  __syncthreads();
  if(threadIdx.x == 0){
    double m = fmax(fmax(red[0], red[1]), fmax(red[2], red[3]));
    atomic_max_d(amax_slot, m);
  }
}

template<int PERM>
__global__ void __launch_bounds__(256) ln_quant(const double* __restrict__ in,
    unsigned short* __restrict__ dst, const float* __restrict__ g,
    const float* __restrict__ bta, const ull* __restrict__ slot){
  int wave = threadIdx.x >> 6, lane = threadIdx.x & 63;
  double s = slot_scale(slot); float sf = (float)s;
  for(int tok = blockIdx.x*4 + wave; tok < M_TOK; tok += gridDim.x*4){
    size_t base = (size_t)tok * E;
    double y0, y1, y2;
    ln_row(in, base, lane, g, bta, y0, y1, y2);
    int d = PERM ? pmap_inv(tok) : tok;
    unsigned short* dr = dst + (size_t)d*KP1;
    dr[lane]       = f2bf(q_int_fast(y0, s, sf));
    dr[lane + 64]  = f2bf(q_int_fast(y1, s, sf));
    dr[lane + 128] = (lane < E - 128) ? f2bf(q_int_fast(y2, s, sf)) : (unsigned short)0;
  }
}

__global__ void __launch_bounds__(256) quant_act(const double* __restrict__ src,
                          unsigned short* __restrict__ dst,
                          const ull* __restrict__ slot){
  int tid = blockIdx.x*256 + threadIdx.x;
  if(tid >= M_TOK*KP1/8) return;
  int idx8 = tid*8;
  int row = idx8 / KP1, k0 = idx8 - row*KP1;
  double s = slot_scale(slot); float sf = (float)s;
  const double* sp = src + (size_t)row*E;
  unsigned short v[8];
  #pragma unroll
  for(int j = 0; j < 8; j++){
    int k = k0 + j;
    v[j] = (k < E) ? f2bf(q_int_fast(sp[k], s, sf)) : (unsigned short)0;
  }
  *reinterpret_cast<short8*>(dst + (size_t)row*KP1 + k0) = *reinterpret_cast<short8*>(v);
}

__global__ void gelu_finalize(ull* slots, int i){
  if(threadIdx.x != 0) return;
  double am = 0.0;
  ull kx = slots[SLOT_GXMAX + i];
  if(kx){ double x = dec_d(kx); if(fabs(x) < 1e299) am = fabs(gelu_d(x)); }
  ull ka = slots[SLOT_GXA + i];
  if(ka){ double x = dec_d(ka); if(fabs(x) < 1e299) am = fmax(am, fabs(gelu_d(x))); }
  ull kb = slots[SLOT_GXB + i];
  if(kb != ~0ULL){ double x = dec_d(kb); if(fabs(x) < 1e299) am = fmax(am, fabs(gelu_d(x))); }
  am = fmax(am, __longlong_as_double((long long)slots[SLOT_GDIR + i]));
  slots[SLOT_GELU + i] = (ull)__double_as_longlong(am);
}

// fused Q/K/V GEMM (K-loop already compile-time: KP1/32)
__global__ void __launch_bounds__(256) gemm_qkv(
    const unsigned short* __restrict__ A8,
    const unsigned short* __restrict__ Wq, float* __restrict__ outq)
{
  int sel = blockIdx.x;
  const unsigned short* W8 = Wq + (size_t)sel*36864;
  float* outF = outq + (size_t)sel*((size_t)M_TOK*E);
  int wave = threadIdx.x >> 6, lane = threadIdx.x & 63;
  int m0 = blockIdx.y*64 + wave*16;
  int lr = lane & 15, lg = lane >> 4;
  const unsigned short* Arow = A8 + (size_t)(m0 + lr)*KP1 + lg*8;
  const unsigned short* Wbase = W8 + (size_t)lr*KP1 + lg*8;
  f32x4 acc[12];
  #pragma unroll
  for(int j = 0; j < 12; j++) acc[j] = (f32x4){0.f,0.f,0.f,0.f};
  #pragma unroll
  for(int kk = 0; kk < KP1/32; kk++){
    short8 a = *reinterpret_cast<const short8*>(Arow + kk*32);
    const unsigned short* Wp = Wbase + kk*32;
    #pragma unroll
    for(int j = 0; j < 12; j++){
      short8 b = *reinterpret_cast<const short8*>(Wp + (size_t)j*16*KP1);
      acc[j] = __builtin_amdgcn_mfma_f32_16x16x32_bf16(a, b, acc[j], 0, 0, 0);
    }
  }
  #pragma unroll
  for(int j = 0; j < 12; j++){
    int col = j*16 + lr;
    if(col >= E) continue;
    #pragma unroll
    for(int r = 0; r < 4; r++){
      int row = m0 + lg*4 + r;
      outF[(size_t)row*E + col] = acc[j][r];
    }
  }
}

// MFMA GEMM, K-loop fully unrolled (KSTEPS compile-time).
// EPI 2: gelu-amax candidates only (no store);
// EPI 3: f64 residual into h (prefetched before K-loop) + fused LN amax;
// EPI 4: fused gelu + quantize, LDS-staged coalesced bf16 store to outU16 [M][KP2].
template<int KSTEPS, int NT, int EPI>
__global__ void __launch_bounds__(256) gemm_mfma(
    const unsigned short* __restrict__ A8,
    const unsigned short* __restrict__ W8,
    const float* __restrict__ bias, int Nreal,
    double* __restrict__ outH, unsigned short* __restrict__ outU16,
    const ull* __restrict__ slotA, const ull* __restrict__ slotW,
    const ull* __restrict__ slotG,
    ull* cand, int permOut,
    const float* __restrict__ lng, const float* __restrict__ lnb)
{
  constexpr int Kpad = KSTEPS*32;
  int wave = threadIdx.x >> 6, lane = threadIdx.x & 63;
  int m0 = blockIdx.y*64 + wave*16;
  int tbase = blockIdx.x*NT;
  int lr = lane & 15, lg = lane >> 4;
  const unsigned short* Arow = A8 + (size_t)(m0 + lr)*Kpad + lg*8;
  const unsigned short* Wbase = W8 + (size_t)(tbase*16 + lr)*Kpad + lg*8;

  // EPI=3: prefetch h BEFORE the K-loop to hide HBM latency under MFMA
  double hv[EPI == 3 ? 4 : 1][EPI == 3 ? NT : 1];
  int orow_r[EPI == 3 ? 4 : 1];
  if constexpr (EPI == 3){
    #pragma unroll
    for(int r = 0; r < 4; r++){
      int row = m0 + lg*4 + r;
      orow_r[r] = pmap(row, permOut);
      #pragma unroll
      for(int j = 0; j < NT; j++){
        int col = j*16 + lr;
        hv[r][j] = (col < Nreal) ? outH[(size_t)orow_r[r]*E + col] : 0.0;
      }
    }
  }

  f32x4 acc[NT];
  #pragma unroll
  for(int j = 0; j < NT; j++) acc[j] = (f32x4){0.f,0.f,0.f,0.f};
  #pragma unroll
  for(int kk = 0; kk < KSTEPS; kk++){
    short8 a = *reinterpret_cast<const short8*>(Arow + kk*32);
    const unsigned short* Wp = Wbase + kk*32;
    #pragma unroll
    for(int j = 0; j < NT; j++){
      short8 b = *reinterpret_cast<const short8*>(Wp + (size_t)j*16*Kpad);
      acc[j] = __builtin_amdgcn_mfma_f32_16x16x32_bf16(a, b, acc[j], 0, 0, 0);
    }
  }
  double sAW = slot_scale(slotA) * slot_scale(slotW);

  if constexpr (EPI == 2){
    double xmax = -1e300, xa = -1e300, xb = 1e300, dir = 0.0;
    #pragma unroll
    for(int j = 0; j < NT; j++){
      int col = (tbase + j)*16 + lr;
      if(col >= Nreal) continue;
      #pragma unroll
      for(int r = 0; r < 4; r++){
        double outv = (double)acc[j][r] * sAW + (double)bias[col];
        xmax = fmax(xmax, outv);
        if(outv <= XL) xa = fmax(xa, outv);
        else if(outv < XR) dir = fmax(dir, fabs(gelu_d(outv)));
        if(outv >= XR) xb = fmin(xb, outv);
      }
    }
    for(int m = 32; m > 0; m >>= 1){
      xmax = fmax(xmax, __shfl_xor(xmax, m));
      xa   = fmax(xa,   __shfl_xor(xa,   m));
      xb   = fmin(xb,   __shfl_xor(xb,   m));
      dir  = fmax(dir,  __shfl_xor(dir,  m));
    }
    __shared__ double r0[4], r1[4], r2[4], r3[4];
    if(lane == 0){ r0[wave]=xmax; r1[wave]=xa; r2[wave]=xb; r3[wave]=dir; }
    __syncthreads();
    if(threadIdx.x == 0){
      double M0=r0[0], A0=r1[0], B0=r2[0], D0=r3[0];
      for(int w = 1; w < 4; w++){
        M0 = fmax(M0, r0[w]); A0 = fmax(A0, r1[w]);
        B0 = fmin(B0, r2[w]); D0 = fmax(D0, r3[w]);
      }
      atomicMax(cand + SLOT_GXMAX, enc_d(M0));
      atomicMax(cand + SLOT_GXA,   enc_d(A0));
      atomicMin(cand + SLOT_GXB,   enc_d(B0));
      atomicMax(cand + SLOT_GDIR,  (ull)__double_as_longlong(D0));
    }
  } else if constexpr (EPI == 4){
    // gelu + quantize into wave-private LDS tile, then coalesced 16B stores.
    // Usage guarantees full tile coverage (Nreal multiple of NT*16 per grid).
    __shared__ unsigned short st[4][16][NT*16 + 8];
    double sg = slot_scale(slotG);
    float sAWf = (float)sAW, sgf = (float)sg;
    #pragma unroll
    for(int j = 0; j < NT; j++){
      int col = (tbase + j)*16 + lr;
      #pragma unroll
      for(int r = 0; r < 4; r++){
        float a = acc[j][r];
        float y = fmaf(a, sAWf, bias[col]);
        float gf = gelu_f(y);
        float t = gf / sgf;
        float rq = rintf(t);
        if(fabsf(t - rq) > 0.497f || fabsf(t) > 126.f){
          double outv = (double)a*sAW + (double)bias[col];
          double rd = rint(gelu_d(outv)/sg);
          rd = fmin(fmax(rd, -128.0), 127.0);
          rq = (float)rd;
        }
        st[wave][lg*4 + r][j*16 + lr] = f2bf(rq);
      }
    }
    // wave-private readback -> coalesced global stores (no barrier needed)
    constexpr int CHUNKS = 16 * (NT*2);          // rows * (NT*16/8) 16B-chunks
    #pragma unroll
    for(int it = 0; it < (CHUNKS + 63)/64; it++){
      int c = lane + it*64;
      if(c < CHUNKS){
        int row = c / (NT*2), cc = c - row*(NT*2);
        short8 v = *reinterpret_cast<const short8*>(&st[wave][row][cc*8]);
        *reinterpret_cast<short8*>(outU16 + (size_t)(m0 + row)*KP2
                                   + (size_t)tbase*16 + cc*8) = v;
      }
    }
  } else { // EPI == 3: residual (prefetched) + fused LN amax; tbase==0, NT*16 >= Nreal
    double amx = 0.0;
    #pragma unroll
    for(int r = 0; r < 4; r++){
      int orow = orow_r[r];
      double hvr[NT];
      double rsum = 0.0;
      #pragma unroll
      for(int j = 0; j < NT; j++){
        int col = j*16 + lr;
        double nh = 0.0;
        if(col < Nreal){
          double outv = (double)acc[j][r] * sAW + (double)bias[col];
          nh = hv[r][j] + outv;
          outH[(size_t)orow*E + col] = nh;
        }
        hvr[j] = nh;
        rsum += nh;
      }
      for(int m = 1; m <= 8; m <<= 1) rsum += __shfl_xor(rsum, m);
      double mean = rsum * (1.0 / E);
      double vsum = 0.0;
      #pragma unroll
      for(int j = 0; j < NT; j++){
        int col = j*16 + lr;
        double d_ = (col < Nreal) ? (hvr[j] - mean) : 0.0;
        vsum += d_*d_;
      }
      for(int m = 1; m <= 8; m <<= 1) vsum += __shfl_xor(vsum, m);
      double inv = 1.0 / sqrt(vsum * (1.0 / E) + 1e-5);
      #pragma unroll
      for(int j = 0; j < NT; j++){
        int col = j*16 + lr;
        if(col < Nreal){
          double yy = (hvr[j] - mean)*inv*(double)lng[col] + (double)lnb[col];
          amx = fmax(amx, fabs(yy));
        }
      }
    }
    for(int m = 1; m <= 32; m <<= 1) amx = fmax(amx, __shfl_xor(amx, m));
    __shared__ double redA[4];
    if(lane == 0) redA[wave] = amx;
    __syncthreads();
    if(threadIdx.x == 0)
      atomic_max_d(cand, fmax(fmax(redA[0], redA[1]), fmax(redA[2], redA[3])));
  }
}

// attention v2: raw-int f32 LDS, transposed K, bias expansion, 4 segments/block
template<int L>
__global__ void __launch_bounds__(64) attn_v2(const float* __restrict__ qa,
    const float* __restrict__ ka, const float* __restrict__ va,
    double* __restrict__ o,
    const float* __restrict__ bq, const float* __restrict__ bk,
    const float* __restrict__ bv,
    const ull* __restrict__ sLN, const ull* __restrict__ sWq,
    const ull* __restrict__ sWk, const ull* __restrict__ sWv,
    ull* amax_slot){
  const int LP = L + 1;
  __shared__ float qs[L*DH], kT[DH*L], vs[L*DH];
  __shared__ double att[L*LP];
  __shared__ double QB[L], KB[L], BBs;
  int tid = threadIdx.x;
  double sA = slot_scale(sLN);
  double dq = sA * slot_scale(sWq);
  double dk = sA * slot_scale(sWk);
  double dv = sA * slot_scale(sWv);
  double dqk = dq * dk;
  double am = 0.0;
  for(int gseg = 0; gseg < 4; gseg++){
    int segid = blockIdx.x*4 + gseg;
    int n = segid / HH, hh = segid % HH;
    size_t rowbase = (size_t)n*L*E + hh*DH;
    const float* bqh = bq + hh*DH;
    const float* bkh = bk + hh*DH;
    const float* bvh = bv + hh*DH;
    for(int idx = tid; idx < L*DH; idx += 64){
      int l = idx / DH, d = idx - l*DH;
      size_t g = rowbase + (size_t)l*E + d;
      qs[l*DH+d] = qa[g];
      kT[d*L+l]  = ka[g];
      vs[l*DH+d] = va[g];
    }
    __syncthreads();
    if(tid < L){
      double s = 0.0;
      for(int d = 0; d < DH; d++) s += (double)qs[tid*DH+d] * (double)bkh[d];
      QB[tid] = s;
    } else if(tid >= 16 && tid < 16 + L){
      int m = tid - 16;
      double s = 0.0;
      for(int d = 0; d < DH; d++) s += (double)kT[d*L+m] * (double)bqh[d];
      KB[m] = s;
    } else if(tid == 63){
      double s = 0.0;
      for(int d = 0; d < DH; d++) s += (double)bqh[d] * (double)bkh[d];
      BBs = s;
    }
    __syncthreads();
    for(int idx = tid; idx < L*L; idx += 64){
      int l = idx / L, m = idx - l*L;
      double si = 0.0;                    // exact integer dot (<= 3e14 < 2^53)
      for(int d = 0; d < DH; d++) si += (double)qs[l*DH+d] * (double)kT[d*L+m];
      att[l*LP+m] = (dqk*si + dq*QB[l] + dk*KB[m] + BBs) * (1.0 / 6.0);
    }
    __syncthreads();
    if(tid < L){
      double mx = -1e300;
      for(int m = 0; m < L; m++) mx = fmax(mx, att[tid*LP+m]);
      double sm = 0.0;
      for(int m = 0; m < L; m++){ double e_ = exp(att[tid*LP+m] - mx); att[tid*LP+m] = e_; sm += e_; }
      double r = 1.0 / sm;
      for(int m = 0; m < L; m++) att[tid*LP+m] *= r;
    }
    __syncthreads();
    for(int idx = tid; idx < L*DH; idx += 64){
      int l = idx / DH, d = idx - l*DH;
      double bvd = (double)bvh[d];
      double s = 0.0;
      for(int m = 0; m < L; m++) s += att[l*LP+m] * ((double)vs[m*DH+d]*dv + bvd);
      o[rowbase + (size_t)l*E + d] = s;
      am = fmax(am, fabs(s));
    }
    __syncthreads();
  }
  for(int m = 32; m > 0; m >>= 1) am = fmax(am, __shfl_xor(am, m));
  if(tid == 0) atomic_max_d(amax_slot, am);
}

__global__ void __launch_bounds__(256) pooled_kernel(const double* __restrict__ lnout,
    double* __restrict__ pooled, const ull* __restrict__ slot_ln,
    ull* slot_pooled){
  int tid = blockIdx.x*256 + threadIdx.x;
  double am = 0.0;
  if(tid < Bb*E){
    int b = tid / E, e = tid - (tid/E)*E;
    double sl = slot_scale(slot_ln); float slf = (float)sl;
    double sum = 0.0;
    for(int s = 0; s < S; s++)
      sum += (double)q_int_fast(lnout[((size_t)b*S + s)*E + e], sl, slf) * sl;
    double pv = sum * (1.0 / S);
    pooled[(size_t)b*E + e] = pv;
    am = fabs(pv);
  }
  for(int m = 32; m > 0; m >>= 1) am = fmax(am, __shfl_xor(am, m));
  if((threadIdx.x & 63) == 0) atomic_max_d(slot_pooled, am);
}

__global__ void __launch_bounds__(64) cls_kernel(const double* __restrict__ pooled,
    const float* __restrict__ cw, const float* __restrict__ cb,
    float* __restrict__ out, const ull* __restrict__ sp,
    const ull* __restrict__ sw){
  int tid = blockIdx.x*64 + threadIdx.x;
  if(tid >= Bb*4) return;
  int b = tid >> 2, j = tid & 3;
  double s1 = slot_scale(sp), s2 = slot_scale(sw);
  float acc = 0.f;
  for(int e = 0; e < E; e++)
    acc += q_int_d(pooled[b*E + e], s1) * q_int_d((double)cw[j*E + e], s2);
  out[tid] = (float)((double)acc * (s1 * s2) + (double)cb[j]);
}

extern "C" void kernel_launch(void* const* d_in, const int* in_sizes, int n_in,
                              void* d_out, int out_size, void* d_ws, size_t ws_size,
                              hipStream_t stream){
  const float* x      = (const float*)d_in[0];
  const float* proj_w = (const float*)d_in[1];
  const float* proj_b = (const float*)d_in[2];
  const float* ln1_g  = (const float*)d_in[3];
  const float* ln1_b  = (const float*)d_in[4];
  const float* wq     = (const float*)d_in[5];
  const float* bq     = (const float*)d_in[6];
  const float* wk     = (const float*)d_in[7];
  const float* bk     = (const float*)d_in[8];
  const float* wv     = (const float*)d_in[9];
  const float* bv     = (const float*)d_in[10];
  const float* wo     = (const float*)d_in[11];
  const float* bo     = (const float*)d_in[12];
  const float* ln2_g  = (const float*)d_in[13];
  const float* ln2_b  = (const float*)d_in[14];
  const float* fc1_w  = (const float*)d_in[15];
  const float* fc1_b  = (const float*)d_in[16];
  const float* fc2_w  = (const float*)d_in[17];
  const float* fc2_b  = (const float*)d_in[18];
  const float* fn_g   = (const float*)d_in[19];
  const float* fn_b   = (const float*)d_in[20];
  const float* cls_w  = (const float*)d_in[21];
  const float* cls_b  = (const float*)d_in[22];
  float* outp = (float*)d_out;

  char* base = (char*)d_ws;
  ull*    slots  = (ull*)base;                                       // 4 KiB
  double* h      = (double*)(base + 4096);                           // 41.3 MB
  double* scr    = h + BUF;                                          // attn o / final LN
  float*  facc   = (float*)(scr + BUF);                              // arena (q/k/v accs)
  float*  qacc   = facc;
  double* pooled = (double*)facc;
  unsigned short* act8 = (unsigned short*)(facc + (size_t)M_TOK*MLPD);
  unsigned short* mid8 = act8 + (size_t)M_TOK*KP1;
  unsigned short* w8   = mid8 + (size_t)M_TOK*KP2;

  init_slots<<<1, 128, 0, stream>>>(slots);
  zero_pad<<<(M_TOK*2 + 255)/256, 256, 0, stream>>>(mid8);

  amax_f32<<<dim3(32,1), 256, 0, stream>>>(x,      Bb*CC*TT, slots + SLOT_X);
  amax_f32<<<dim3(1,1),  256, 0, stream>>>(proj_w, E*CC,     slots + SLOT_PW);
  amax_f32<<<dim3(1,1),  256, 0, stream>>>(cls_w,  4*E,      slots + SLOT_CW);
  amax_f32<<<dim3(4,NBLK),  256, 0, stream>>>(wq,    E*E,    slots + SLOT_WQ);
  amax_f32<<<dim3(4,NBLK),  256, 0, stream>>>(wk,    E*E,    slots + SLOT_WK);
  amax_f32<<<dim3(4,NBLK),  256, 0, stream>>>(wv,    E*E,    slots + SLOT_WV);
  amax_f32<<<dim3(4,NBLK),  256, 0, stream>>>(wo,    E*E,    slots + SLOT_WO);
  amax_f32<<<dim3(16,NBLK), 256, 0, stream>>>(fc1_w, MLPD*E, slots + SLOT_FC1);
  amax_f32<<<dim3(16,NBLK), 256, 0, stream>>>(fc2_w, MLPD*E, slots + SLOT_FC2);

  quant_w<<<dim3((KP1*KP1+255)/256, NBLK), 256, 0, stream>>>(wq, E, E, KP1, KP1, slots+SLOT_WQ, w8, WQ8_OFF);
  quant_w<<<dim3((KP1*KP1+255)/256, NBLK), 256, 0, stream>>>(wk, E, E, KP1, KP1, slots+SLOT_WK, w8, WK8_OFF);
  quant_w<<<dim3((KP1*KP1+255)/256, NBLK), 256, 0, stream>>>(wv, E, E, KP1, KP1, slots+SLOT_WV, w8, WV8_OFF);
  quant_w<<<dim3((KP1*KP1+255)/256, NBLK), 256, 0, stream>>>(wo, E, E, KP1, KP1, slots+SLOT_WO, w8, WO8_OFF);
  quant_w<<<dim3((MLPD*KP1+255)/256, NBLK), 256, 0, stream>>>(fc1_w, MLPD, E, MLPD, KP1, slots+SLOT_FC1, w8, FC18_OFF);
  quant_w<<<dim3((KP1*KP2+255)/256, NBLK), 256, 0, stream>>>(fc2_w, E, MLPD, KP1, KP2, slots+SLOT_FC2, w8, FC28_OFF);

  proj_bcast<<<(Bb*TT*E + 255)/256, 256, 0, stream>>>(x, proj_w, proj_b, h,
                                                      slots + SLOT_X, slots + SLOT_PW);

  const int QA_GRID = (M_TOK*KP1/8 + 255)/256;
  const int LN_GRID = 1792;

  // block-0 LN1 amax (later blocks get it fused into the fc2 epilogue)
  ln_amax<false><<<LN_GRID, 256, 0, stream>>>(h, nullptr, ln1_g, ln1_b, slots + SLOT_LN1);

  for(int i = 0; i < NBLK; i++){
    int pi = i & 1;
    const unsigned short* wb = w8 + (size_t)i*WBLK;
    // recompute LN1 + quantize (perm for odd blocks)
    if(pi == 0)
      ln_quant<0><<<LN_GRID, 256, 0, stream>>>(h, act8, ln1_g + i*E, ln1_b + i*E, slots + SLOT_LN1 + i);
    else
      ln_quant<1><<<LN_GRID, 256, 0, stream>>>(h, act8, ln1_g + i*E, ln1_b + i*E, slots + SLOT_LN1 + i);
    // fused QKV GEMMs
    gemm_qkv<<<dim3(3, M_TOK/64), 256, 0, stream>>>(act8, wb + WQ8_OFF, qacc);
    // attention -> scr (f64) + amax
    if(pi == 0){
      int nseg = (M_TOK/TT)*HH;
      attn_v2<TT><<<nseg/4, 64, 0, stream>>>(qacc, qacc + (size_t)M_TOK*E, qacc + (size_t)2*M_TOK*E, scr,
          bq + i*E, bk + i*E, bv + i*E,
          slots+SLOT_LN1+i, slots+SLOT_WQ+i, slots+SLOT_WK+i, slots+SLOT_WV+i,
          slots + SLOT_O + i);
    } else {
      int nseg = (M_TOK/CC)*HH;
      attn_v2<CC><<<nseg/4, 64, 0, stream>>>(qacc, qacc + (size_t)M_TOK*E, qacc + (size_t)2*M_TOK*E, scr,
          bq + i*E, bk + i*E, bv + i*E,
          slots+SLOT_LN1+i, slots+SLOT_WQ+i, slots+SLOT_WK+i, slots+SLOT_WV+i,
          slots + SLOT_O + i);
    }
    // quantize o -> act8
    quant_act<<<QA_GRID, 256, 0, stream>>>(scr, act8, slots + SLOT_O + i);
    // WO GEMM + residual (prefetched) + fused LN2 amax
    gemm_mfma<6,12,3><<<dim3(1, M_TOK/64), 256, 0, stream>>>(act8, wb + WO8_OFF, bo + i*E, E,
        h, nullptr, slots+SLOT_O+i, slots+SLOT_WO+i, nullptr, slots+SLOT_LN2+i, pi,
        ln2_g + i*E, ln2_b + i*E);
    // recompute LN2 + quantize
    ln_quant<0><<<LN_GRID, 256, 0, stream>>>(h, act8, ln2_g + i*E, ln2_b + i*E, slots + SLOT_LN2 + i);
    // fc1 pass 1: gelu-amax candidates only (no store)
    gemm_mfma<6,9,2><<<dim3(5, M_TOK/64), 256, 0, stream>>>(act8, wb + FC18_OFF, fc1_b + i*MLPD, MLPD,
        nullptr, nullptr, slots+SLOT_LN2+i, slots+SLOT_FC1+i, nullptr, slots + i, 0, nullptr, nullptr);
    gelu_finalize<<<1, 64, 0, stream>>>(slots, i);
    // fc1 pass 2: fused gelu + quantize -> mid8 (bf16, coalesced via LDS)
    gemm_mfma<6,9,4><<<dim3(5, M_TOK/64), 256, 0, stream>>>(act8, wb + FC18_OFF, fc1_b + i*MLPD, MLPD,
        nullptr, mid8, slots+SLOT_LN2+i, slots+SLOT_FC1+i, slots+SLOT_GELU+i, nullptr, 0, nullptr, nullptr);
    // fc2 GEMM + residual (prefetched) + fused next-LN amax
    ull* nslot = (i < 5) ? (slots + SLOT_LN1 + i + 1) : (slots + SLOT_FLN);
    const float* ng = (i < 5) ? (ln1_g + (i+1)*E) : fn_g;
    const float* nb = (i < 5) ? (ln1_b + (i+1)*E) : fn_b;
    gemm_mfma<23,12,3><<<dim3(1, M_TOK/64), 256, 0, stream>>>(mid8, wb + FC28_OFF, fc2_b + i*E, E,
        h, nullptr, slots+SLOT_GELU+i, slots+SLOT_FC2+i, nullptr, nslot, 0, ng, nb);
  }

  // final LN writes rows for pooling (amax already fused; extra atomicMax harmless)
  ln_amax<true><<<LN_GRID, 256, 0, stream>>>(h, scr, fn_g, fn_b, slots + SLOT_FLN);
  pooled_kernel<<<(Bb*E + 255)/256, 256, 0, stream>>>(scr, pooled, slots + SLOT_FLN, slots + SLOT_POOL);
  cls_kernel<<<(Bb*4 + 63)/64, 64, 0, stream>>>(pooled, cls_w, cls_b, outp,
                                                slots + SLOT_POOL, slots + SLOT_CW);
}

// Round 12
// 3206.818 us; speedup vs baseline: 1.1087x; 1.1087x over previous
//
#include <hip/hip_runtime.h>
#include <math.h>

#define E 180
#define S 112
#define Bb 256
#define CC 14
#define TT 8
#define HH 5
#define DH 36
#define NBLK 6
#define MLPD 720
#define M_TOK (Bb*S)              // 28672
#define BUF ((size_t)M_TOK * E)   // 5,160,960 elements

#define KP1 192                   // padded K for E=180 (6x32)
#define KP2 736                   // padded K for 720 (23x32)

// W8 arena per-block element offsets
#define WQ8_OFF   0
#define WK8_OFF   36864
#define WV8_OFF   73728
#define WO8_OFF   110592
#define FC18_OFF  147456
#define FC28_OFF  285696
#define WBLK      427008

// amax slot indices (each slot = double bits in unsigned long long)
#define SLOT_X    0
#define SLOT_PW   1
#define SLOT_CW   2
#define SLOT_POOL 3
#define SLOT_FLN  4
#define SLOT_WQ   8
#define SLOT_WK   16
#define SLOT_WV   24
#define SLOT_WO   32
#define SLOT_FC1  40
#define SLOT_FC2  48
#define SLOT_LN1  56
#define SLOT_O    64
#define SLOT_LN2  72
#define SLOT_GELU 80
// gelu-amax candidate slots (per transformer block)
#define SLOT_GXMAX 88
#define SLOT_GXA   96
#define SLOT_GXB   104
#define SLOT_GDIR  112

#define XL (-0.7535)
#define XR (-0.7515)

typedef unsigned long long ull;
typedef __attribute__((ext_vector_type(8))) short short8;
typedef __attribute__((ext_vector_type(4))) float f32x4;

__device__ __forceinline__ double slot_scale(const ull* s){
  return fmax(__longlong_as_double((long long)*s) / 127.0, 1e-8);
}
__device__ __forceinline__ void atomic_max_d(ull* p, double v){
  atomicMax(p, (ull)__double_as_longlong(v));   // v >= 0 -> bit-monotone
}
__device__ __forceinline__ ull enc_d(double d){
  ull b = (ull)__double_as_longlong(d);
  return (b >> 63) ? ~b : (b | 0x8000000000000000ULL);
}
__device__ __forceinline__ double dec_d(ull k){
  ull b = (k >> 63) ? (k ^ 0x8000000000000000ULL) : ~k;
  return __longlong_as_double((long long)b);
}
__device__ __forceinline__ float q_int_d(double x, double s){
  double r = rint(x / s);
  r = fmin(fmax(r, -128.0), 127.0);
  return (float)r;
}
__device__ __forceinline__ float q_int_fast(double x, double s, float sf){
  float t = (float)x / sf;
  float r = rintf(t);
  if(fabsf(t - r) > 0.497f || fabsf(t) > 126.f){
    double rd = rint(x / s);
    rd = fmin(fmax(rd, -128.0), 127.0);
    return (float)rd;
  }
  return r;
}
__device__ __forceinline__ unsigned short f2bf(float f){
  return (unsigned short)(__float_as_uint(f) >> 16);
}
__device__ __forceinline__ double gelu_d(double x){
  double t = tanh(0.7978845608028654*(x + 0.044715*x*x*x));
  return 0.5*x*(1.0 + t);
}
__device__ __forceinline__ float gelu_f(float x){
  float t = tanhf(0.7978845608f*(x + 0.044715f*x*x*x));
  return 0.5f*x*(1.f + t);
}
__device__ __forceinline__ int pmap(int row, int mode){
  if(mode == 0) return row;
  int b = row / S; int r = row - b*S; int t = r / CC; int c = r - t*CC;
  return b*S + c*TT + t;
}
__device__ __forceinline__ int pmap_inv(int row){
  int b = row / S; int r = row - b*S; int c = r / TT; int t = r - c*TT;
  return b*S + t*CC + c;
}

__global__ void init_slots(ull* slots){
  int t = threadIdx.x;
  slots[t] = (t >= SLOT_GXB && t < SLOT_GXB + NBLK) ? ~0ULL : 0ULL;
}

// zero the pad columns (720..735) of mid8 once
__global__ void zero_pad(unsigned short* __restrict__ mid8){
  int tid = blockIdx.x*256 + threadIdx.x;
  if(tid >= M_TOK*2) return;
  int row = tid >> 1, half = tid & 1;
  short8 z = (short8){0,0,0,0,0,0,0,0};
  *reinterpret_cast<short8*>(mid8 + (size_t)row*KP2 + MLPD + half*8) = z;
}

__global__ void amax_f32(const float* __restrict__ src, int seglen, ull* slots){
  int seg = blockIdx.y;
  const float* p = src + (size_t)seg * seglen;
  float m = 0.f;
  for(int i = blockIdx.x*256 + threadIdx.x; i < seglen; i += gridDim.x*256)
    m = fmaxf(m, fabsf(p[i]));
  __shared__ float red[256];
  red[threadIdx.x] = m;
  __syncthreads();
  for(int off = 128; off > 0; off >>= 1){
    if(threadIdx.x < off) red[threadIdx.x] = fmaxf(red[threadIdx.x], red[threadIdx.x+off]);
    __syncthreads();
  }
  if(threadIdx.x == 0) atomic_max_d(slots + seg, (double)red[0]);
}

__global__ void quant_w(const float* __restrict__ src, int N, int K,
                        int Npad, int Kpad, const ull* __restrict__ slotbase,
                        unsigned short* __restrict__ dst, size_t dstoff){
  int i = blockIdx.y;
  int e = blockIdx.x*256 + threadIdx.x;
  int tot = Npad * Kpad;
  if(e >= tot) return;
  int n = e / Kpad, k = e - n*Kpad;
  double s = slot_scale(slotbase + i);
  float val = 0.f;
  if(n < N && k < K)
    val = q_int_d((double)src[(size_t)i*N*K + (size_t)n*K + k], s);
  dst[(size_t)i*WBLK + dstoff + e] = f2bf(val);
}

__global__ void proj_bcast(const float* __restrict__ x, const float* __restrict__ pw,
                           const float* __restrict__ pb, double* __restrict__ h,
                           const ull* __restrict__ sx_slot,
                           const ull* __restrict__ sw_slot){
  int tid = blockIdx.x*256 + threadIdx.x;
  if(tid >= Bb*TT*E) return;
  int e = tid % E; int bt = tid / E; int t = bt % TT; int b = bt / TT;
  double sx = slot_scale(sx_slot), sw = slot_scale(sw_slot);
  float acc = 0.f;
  for(int c = 0; c < CC; c++)
    acc += q_int_d((double)x[(b*CC + c)*TT + t], sx) * q_int_d((double)pw[e*CC + c], sw);
  double o = (double)acc * (sx * sw) + (double)pb[e];
  for(int c = 0; c < CC; c++)
    h[((size_t)b*S + c*TT + t)*E + e] = o;
}

// shared LN row computation (bit-identical between passes that use it)
__device__ __forceinline__ void ln_row(const double* __restrict__ in, size_t base, int lane,
    const float* __restrict__ g, const float* __restrict__ bta,
    double& y0, double& y1, double& y2){
  double x0 = in[base + lane];
  double x1 = in[base + lane + 64];
  double x2 = (lane < E - 128) ? in[base + lane + 128] : 0.0;
  double sum = x0 + x1 + x2;
  for(int m = 32; m > 0; m >>= 1) sum += __shfl_xor(sum, m);
  double mean = sum * (1.0 / E);
  double d0 = x0 - mean, d1 = x1 - mean;
  double d2 = (lane < E - 128) ? (x2 - mean) : 0.0;
  double vs = d0*d0 + d1*d1 + d2*d2;
  for(int m = 32; m > 0; m >>= 1) vs += __shfl_xor(vs, m);
  double inv = 1.0 / sqrt(vs * (1.0 / E) + 1e-5);
  y0 = d0*inv*(double)g[lane]      + (double)bta[lane];
  y1 = d1*inv*(double)g[lane+64]   + (double)bta[lane+64];
  y2 = (lane < E - 128) ? (d2*inv*(double)g[lane+128] + (double)bta[lane+128]) : 0.0;
}

template<bool WRITE>
__global__ void __launch_bounds__(256) ln_amax(const double* __restrict__ in,
    double* __restrict__ out, const float* __restrict__ g,
    const float* __restrict__ bta, ull* amax_slot){
  int wave = threadIdx.x >> 6, lane = threadIdx.x & 63;
  double amx = 0.0;
  for(int tok = blockIdx.x*4 + wave; tok < M_TOK; tok += gridDim.x*4){
    size_t base = (size_t)tok * E;
    double y0, y1, y2;
    ln_row(in, base, lane, g, bta, y0, y1, y2);
    if(WRITE){
      out[base + lane]      = y0;
      out[base + lane + 64] = y1;
      if(lane < E - 128) out[base + lane + 128] = y2;
    }
    amx = fmax(amx, fmax(fabs(y0), fabs(y1)));
    if(lane < E - 128) amx = fmax(amx, fabs(y2));
  }
  for(int m = 32; m > 0; m >>= 1) amx = fmax(amx, __shfl_xor(amx, m));
  __shared__ double red[4];
  if(lane == 0) red[wave] = amx;
  __syncthreads();
  if(threadIdx.x == 0){
    double m = fmax(fmax(red[0], red[1]), fmax(red[2], red[3]));
    atomic_max_d(amax_slot, m);
  }
}

template<int PERM>
__global__ void __launch_bounds__(256) ln_quant(const double* __restrict__ in,
    unsigned short* __restrict__ dst, const float* __restrict__ g,
    const float* __restrict__ bta, const ull* __restrict__ slot){
  int wave = threadIdx.x >> 6, lane = threadIdx.x & 63;
  double s = slot_scale(slot); float sf = (float)s;
  for(int tok = blockIdx.x*4 + wave; tok < M_TOK; tok += gridDim.x*4){
    size_t base = (size_t)tok * E;
    double y0, y1, y2;
    ln_row(in, base, lane, g, bta, y0, y1, y2);
    int d = PERM ? pmap_inv(tok) : tok;
    unsigned short* dr = dst + (size_t)d*KP1;
    dr[lane]       = f2bf(q_int_fast(y0, s, sf));
    dr[lane + 64]  = f2bf(q_int_fast(y1, s, sf));
    dr[lane + 128] = (lane < E - 128) ? f2bf(q_int_fast(y2, s, sf)) : (unsigned short)0;
  }
}

__global__ void __launch_bounds__(256) quant_act(const double* __restrict__ src,
                          unsigned short* __restrict__ dst,
                          const ull* __restrict__ slot){
  int tid = blockIdx.x*256 + threadIdx.x;
  if(tid >= M_TOK*KP1/8) return;
  int idx8 = tid*8;
  int row = idx8 / KP1, k0 = idx8 - row*KP1;
  double s = slot_scale(slot); float sf = (float)s;
  const double* sp = src + (size_t)row*E;
  unsigned short v[8];
  #pragma unroll
  for(int j = 0; j < 8; j++){
    int k = k0 + j;
    v[j] = (k < E) ? f2bf(q_int_fast(sp[k], s, sf)) : (unsigned short)0;
  }
  *reinterpret_cast<short8*>(dst + (size_t)row*KP1 + k0) = *reinterpret_cast<short8*>(v);
}

__global__ void gelu_finalize(ull* slots, int i){
  if(threadIdx.x != 0) return;
  double am = 0.0;
  ull kx = slots[SLOT_GXMAX + i];
  if(kx){ double x = dec_d(kx); if(fabs(x) < 1e299) am = fabs(gelu_d(x)); }
  ull ka = slots[SLOT_GXA + i];
  if(ka){ double x = dec_d(ka); if(fabs(x) < 1e299) am = fmax(am, fabs(gelu_d(x))); }
  ull kb = slots[SLOT_GXB + i];
  if(kb != ~0ULL){ double x = dec_d(kb); if(fabs(x) < 1e299) am = fmax(am, fabs(gelu_d(x))); }
  am = fmax(am, __longlong_as_double((long long)slots[SLOT_GDIR + i]));
  slots[SLOT_GELU + i] = (ull)__double_as_longlong(am);
}

// fused Q/K/V GEMM
__global__ void __launch_bounds__(256) gemm_qkv(
    const unsigned short* __restrict__ A8,
    const unsigned short* __restrict__ Wq, float* __restrict__ outq)
{
  int sel = blockIdx.x;
  const unsigned short* W8 = Wq + (size_t)sel*36864;
  float* outF = outq + (size_t)sel*((size_t)M_TOK*E);
  int wave = threadIdx.x >> 6, lane = threadIdx.x & 63;
  int m0 = blockIdx.y*64 + wave*16;
  int lr = lane & 15, lg = lane >> 4;
  const unsigned short* Arow = A8 + (size_t)(m0 + lr)*KP1 + lg*8;
  const unsigned short* Wbase = W8 + (size_t)lr*KP1 + lg*8;
  f32x4 acc[12];
  #pragma unroll
  for(int j = 0; j < 12; j++) acc[j] = (f32x4){0.f,0.f,0.f,0.f};
  #pragma unroll
  for(int kk = 0; kk < KP1/32; kk++){
    short8 a = *reinterpret_cast<const short8*>(Arow + kk*32);
    const unsigned short* Wp = Wbase + kk*32;
    #pragma unroll
    for(int j = 0; j < 12; j++){
      short8 b = *reinterpret_cast<const short8*>(Wp + (size_t)j*16*KP1);
      acc[j] = __builtin_amdgcn_mfma_f32_16x16x32_bf16(a, b, acc[j], 0, 0, 0);
    }
  }
  #pragma unroll
  for(int j = 0; j < 12; j++){
    int col = j*16 + lr;
    if(col >= E) continue;
    #pragma unroll
    for(int r = 0; r < 4; r++){
      int row = m0 + lg*4 + r;
      outF[(size_t)row*E + col] = acc[j][r];
    }
  }
}

// MFMA GEMM (4 waves). EPI 2: gelu-amax candidates only (no store);
// EPI 4: fused gelu + quantize, LDS-staged coalesced bf16 store to outU16 [M][KP2].
template<int KSTEPS, int NT, int EPI>
__global__ void __launch_bounds__(256) gemm_mfma(
    const unsigned short* __restrict__ A8,
    const unsigned short* __restrict__ W8,
    const float* __restrict__ bias, int Nreal,
    unsigned short* __restrict__ outU16,
    const ull* __restrict__ slotA, const ull* __restrict__ slotW,
    const ull* __restrict__ slotG, ull* cand)
{
  constexpr int Kpad = KSTEPS*32;
  int wave = threadIdx.x >> 6, lane = threadIdx.x & 63;
  int m0 = blockIdx.y*64 + wave*16;
  int tbase = blockIdx.x*NT;
  int lr = lane & 15, lg = lane >> 4;
  const unsigned short* Arow = A8 + (size_t)(m0 + lr)*Kpad + lg*8;
  const unsigned short* Wbase = W8 + (size_t)(tbase*16 + lr)*Kpad + lg*8;

  f32x4 acc[NT];
  #pragma unroll
  for(int j = 0; j < NT; j++) acc[j] = (f32x4){0.f,0.f,0.f,0.f};
  #pragma unroll
  for(int kk = 0; kk < KSTEPS; kk++){
    short8 a = *reinterpret_cast<const short8*>(Arow + kk*32);
    const unsigned short* Wp = Wbase + kk*32;
    #pragma unroll
    for(int j = 0; j < NT; j++){
      short8 b = *reinterpret_cast<const short8*>(Wp + (size_t)j*16*Kpad);
      acc[j] = __builtin_amdgcn_mfma_f32_16x16x32_bf16(a, b, acc[j], 0, 0, 0);
    }
  }
  double sAW = slot_scale(slotA) * slot_scale(slotW);

  if constexpr (EPI == 2){
    double xmax = -1e300, xa = -1e300, xb = 1e300, dir = 0.0;
    #pragma unroll
    for(int j = 0; j < NT; j++){
      int col = (tbase + j)*16 + lr;
      if(col >= Nreal) continue;
      #pragma unroll
      for(int r = 0; r < 4; r++){
        double outv = (double)acc[j][r] * sAW + (double)bias[col];
        xmax = fmax(xmax, outv);
        if(outv <= XL) xa = fmax(xa, outv);
        else if(outv < XR) dir = fmax(dir, fabs(gelu_d(outv)));
        if(outv >= XR) xb = fmin(xb, outv);
      }
    }
    for(int m = 32; m > 0; m >>= 1){
      xmax = fmax(xmax, __shfl_xor(xmax, m));
      xa   = fmax(xa,   __shfl_xor(xa,   m));
      xb   = fmin(xb,   __shfl_xor(xb,   m));
      dir  = fmax(dir,  __shfl_xor(dir,  m));
    }
    __shared__ double r0[4], r1[4], r2[4], r3[4];
    if(lane == 0){ r0[wave]=xmax; r1[wave]=xa; r2[wave]=xb; r3[wave]=dir; }
    __syncthreads();
    if(threadIdx.x == 0){
      double M0=r0[0], A0=r1[0], B0=r2[0], D0=r3[0];
      for(int w = 1; w < 4; w++){
        M0 = fmax(M0, r0[w]); A0 = fmax(A0, r1[w]);
        B0 = fmin(B0, r2[w]); D0 = fmax(D0, r3[w]);
      }
      atomicMax(cand + SLOT_GXMAX, enc_d(M0));
      atomicMax(cand + SLOT_GXA,   enc_d(A0));
      atomicMin(cand + SLOT_GXB,   enc_d(B0));
      atomicMax(cand + SLOT_GDIR,  (ull)__double_as_longlong(D0));
    }
  } else { // EPI == 4: gelu+quantize -> LDS tile -> coalesced 16B stores (full tiles)
    __shared__ unsigned short st[4][16][NT*16 + 8];
    double sg = slot_scale(slotG);
    float sAWf = (float)sAW, sgf = (float)sg;
    #pragma unroll
    for(int j = 0; j < NT; j++){
      int col = (tbase + j)*16 + lr;
      #pragma unroll
      for(int r = 0; r < 4; r++){
        float a = acc[j][r];
        float y = fmaf(a, sAWf, bias[col]);
        float gf = gelu_f(y);
        float t = gf / sgf;
        float rq = rintf(t);
        if(fabsf(t - rq) > 0.497f || fabsf(t) > 126.f){
          double outv = (double)a*sAW + (double)bias[col];
          double rd = rint(gelu_d(outv)/sg);
          rd = fmin(fmax(rd, -128.0), 127.0);
          rq = (float)rd;
        }
        st[wave][lg*4 + r][j*16 + lr] = f2bf(rq);
      }
    }
    constexpr int CHUNKS = 16 * (NT*2);
    #pragma unroll
    for(int it = 0; it < (CHUNKS + 63)/64; it++){
      int c = lane + it*64;
      if(c < CHUNKS){
        int row = c / (NT*2), cc = c - row*(NT*2);
        short8 v = *reinterpret_cast<const short8*>(&st[wave][row][cc*8]);
        *reinterpret_cast<short8*>(outU16 + (size_t)(m0 + row)*KP2
                                   + (size_t)tbase*16 + cc*8) = v;
      }
    }
  }
}

// GEMM + f64 residual into h + fused LN amax, N split across paired waves.
// 8 waves: wave = rowgrp(0..3) + 4*half; pair (w, w+4) shares rows, splits 12 tiles.
template<int KSTEPS>
__global__ void __launch_bounds__(512) gemm_res_ln(
    const unsigned short* __restrict__ A8,
    const unsigned short* __restrict__ W8,
    const float* __restrict__ bias,
    double* __restrict__ h,
    const ull* __restrict__ slotA, const ull* __restrict__ slotW,
    ull* amax_slot, int permOut,
    const float* __restrict__ lng, const float* __restrict__ lnb)
{
  constexpr int Kpad = KSTEPS*32;
  constexpr int NT = 6;
  int wave = threadIdx.x >> 6, lane = threadIdx.x & 63;
  int rowgrp = wave & 3, half = wave >> 2;
  int m0 = blockIdx.x*64 + rowgrp*16;
  int tbase = half*NT;
  int lr = lane & 15, lg = lane >> 4;
  const unsigned short* Arow = A8 + (size_t)(m0 + lr)*Kpad + lg*8;
  const unsigned short* Wbase = W8 + (size_t)(tbase*16 + lr)*Kpad + lg*8;

  // prefetch h before K-loop (residual inputs; rows block-disjoint)
  double hv[4][NT];
  int orow_r[4];
  #pragma unroll
  for(int r = 0; r < 4; r++){
    int row = m0 + lg*4 + r;
    orow_r[r] = pmap(row, permOut);
    #pragma unroll
    for(int j = 0; j < NT; j++){
      int col = (tbase + j)*16 + lr;
      hv[r][j] = (col < E) ? h[(size_t)orow_r[r]*E + col] : 0.0;
    }
  }

  f32x4 acc[NT];
  #pragma unroll
  for(int j = 0; j < NT; j++) acc[j] = (f32x4){0.f,0.f,0.f,0.f};
  #pragma unroll
  for(int kk = 0; kk < KSTEPS; kk++){
    short8 a = *reinterpret_cast<const short8*>(Arow + kk*32);
    const unsigned short* Wp = Wbase + kk*32;
    #pragma unroll
    for(int j = 0; j < NT; j++){
      short8 b = *reinterpret_cast<const short8*>(Wp + (size_t)j*16*Kpad);
      acc[j] = __builtin_amdgcn_mfma_f32_16x16x32_bf16(a, b, acc[j], 0, 0, 0);
    }
  }
  double sAW = slot_scale(slotA) * slot_scale(slotW);

  __shared__ double pr[4][16][2], pv[4][16][2];
  __shared__ double redA[8];

  // residual + partial row-sums (this wave's 6 tiles)
  double rs[4];
  #pragma unroll
  for(int r = 0; r < 4; r++){
    double rsum = 0.0;
    #pragma unroll
    for(int j = 0; j < NT; j++){
      int col = (tbase + j)*16 + lr;
      double nh = 0.0;
      if(col < E){
        double outv = (double)acc[j][r] * sAW + (double)bias[col];
        nh = hv[r][j] + outv;
        h[(size_t)orow_r[r]*E + col] = nh;
      }
      hv[r][j] = nh;
      rsum += nh;
    }
    for(int m = 1; m <= 8; m <<= 1) rsum += __shfl_xor(rsum, m);
    rs[r] = rsum;
  }
  if(lr == 0){
    #pragma unroll
    for(int r = 0; r < 4; r++) pr[rowgrp][lg*4 + r][half] = rs[r];
  }
  __syncthreads();
  double mean_r[4];
  #pragma unroll
  for(int r = 0; r < 4; r++)
    mean_r[r] = (pr[rowgrp][lg*4 + r][0] + pr[rowgrp][lg*4 + r][1]) * (1.0 / E);
  #pragma unroll
  for(int r = 0; r < 4; r++){
    double vsum = 0.0;
    #pragma unroll
    for(int j = 0; j < NT; j++){
      int col = (tbase + j)*16 + lr;
      double d_ = (col < E) ? (hv[r][j] - mean_r[r]) : 0.0;
      vsum += d_*d_;
    }
    for(int m = 1; m <= 8; m <<= 1) vsum += __shfl_xor(vsum, m);
    rs[r] = vsum;
  }
  if(lr == 0){
    #pragma unroll
    for(int r = 0; r < 4; r++) pv[rowgrp][lg*4 + r][half] = rs[r];
  }
  __syncthreads();
  double amx = 0.0;
  #pragma unroll
  for(int r = 0; r < 4; r++){
    double vs = pv[rowgrp][lg*4 + r][0] + pv[rowgrp][lg*4 + r][1];
    double inv = 1.0 / sqrt(vs * (1.0 / E) + 1e-5);
    #pragma unroll
    for(int j = 0; j < NT; j++){
      int col = (tbase + j)*16 + lr;
      if(col < E){
        double yy = (hv[r][j] - mean_r[r])*inv*(double)lng[col] + (double)lnb[col];
        amx = fmax(amx, fabs(yy));
      }
    }
  }
  for(int m = 1; m <= 32; m <<= 1) amx = fmax(amx, __shfl_xor(amx, m));
  if(lane == 0) redA[wave] = amx;
  __syncthreads();
  if(threadIdx.x == 0){
    double mm = redA[0];
    for(int w = 1; w < 8; w++) mm = fmax(mm, redA[w]);
    atomic_max_d(amax_slot, mm);
  }
}

// attention v2: raw-int f32 LDS, transposed K, bias expansion, 4 segments/block
template<int L>
__global__ void __launch_bounds__(64) attn_v2(const float* __restrict__ qa,
    const float* __restrict__ ka, const float* __restrict__ va,
    double* __restrict__ o,
    const float* __restrict__ bq, const float* __restrict__ bk,
    const float* __restrict__ bv,
    const ull* __restrict__ sLN, const ull* __restrict__ sWq,
    const ull* __restrict__ sWk, const ull* __restrict__ sWv,
    ull* amax_slot){
  const int LP = L + 1;
  __shared__ float qs[L*DH], kT[DH*L], vs[L*DH];
  __shared__ double att[L*LP];
  __shared__ double QB[L], KB[L], BBs;
  int tid = threadIdx.x;
  double sA = slot_scale(sLN);
  double dq = sA * slot_scale(sWq);
  double dk = sA * slot_scale(sWk);
  double dv = sA * slot_scale(sWv);
  double dqk = dq * dk;
  double am = 0.0;
  for(int gseg = 0; gseg < 4; gseg++){
    int segid = blockIdx.x*4 + gseg;
    int n = segid / HH, hh = segid % HH;
    size_t rowbase = (size_t)n*L*E + hh*DH;
    const float* bqh = bq + hh*DH;
    const float* bkh = bk + hh*DH;
    const float* bvh = bv + hh*DH;
    for(int idx = tid; idx < L*DH; idx += 64){
      int l = idx / DH, d = idx - l*DH;
      size_t g = rowbase + (size_t)l*E + d;
      qs[l*DH+d] = qa[g];
      kT[d*L+l]  = ka[g];
      vs[l*DH+d] = va[g];
    }
    __syncthreads();
    if(tid < L){
      double s = 0.0;
      for(int d = 0; d < DH; d++) s += (double)qs[tid*DH+d] * (double)bkh[d];
      QB[tid] = s;
    } else if(tid >= 16 && tid < 16 + L){
      int m = tid - 16;
      double s = 0.0;
      for(int d = 0; d < DH; d++) s += (double)kT[d*L+m] * (double)bqh[d];
      KB[m] = s;
    } else if(tid == 63){
      double s = 0.0;
      for(int d = 0; d < DH; d++) s += (double)bqh[d] * (double)bkh[d];
      BBs = s;
    }
    __syncthreads();
    for(int idx = tid; idx < L*L; idx += 64){
      int l = idx / L, m = idx - l*L;
      double si = 0.0;                    // exact integer dot (<= 3e14 < 2^53)
      for(int d = 0; d < DH; d++) si += (double)qs[l*DH+d] * (double)kT[d*L+m];
      att[l*LP+m] = (dqk*si + dq*QB[l] + dk*KB[m] + BBs) * (1.0 / 6.0);
    }
    __syncthreads();
    if(tid < L){
      double mx = -1e300;
      for(int m = 0; m < L; m++) mx = fmax(mx, att[tid*LP+m]);
      double sm = 0.0;
      for(int m = 0; m < L; m++){ double e_ = exp(att[tid*LP+m] - mx); att[tid*LP+m] = e_; sm += e_; }
      double r = 1.0 / sm;
      for(int m = 0; m < L; m++) att[tid*LP+m] *= r;
    }
    __syncthreads();
    for(int idx = tid; idx < L*DH; idx += 64){
      int l = idx / DH, d = idx - l*DH;
      double bvd = (double)bvh[d];
      double s = 0.0;
      for(int m = 0; m < L; m++) s += att[l*LP+m] * ((double)vs[m*DH+d]*dv + bvd);
      o[rowbase + (size_t)l*E + d] = s;
      am = fmax(am, fabs(s));
    }
    __syncthreads();
  }
  for(int m = 32; m > 0; m >>= 1) am = fmax(am, __shfl_xor(am, m));
  if(tid == 0) atomic_max_d(amax_slot, am);
}

__global__ void __launch_bounds__(256) pooled_kernel(const double* __restrict__ lnout,
    double* __restrict__ pooled, const ull* __restrict__ slot_ln,
    ull* slot_pooled){
  int tid = blockIdx.x*256 + threadIdx.x;
  double am = 0.0;
  if(tid < Bb*E){
    int b = tid / E, e = tid - (tid/E)*E;
    double sl = slot_scale(slot_ln); float slf = (float)sl;
    double sum = 0.0;
    for(int s = 0; s < S; s++)
      sum += (double)q_int_fast(lnout[((size_t)b*S + s)*E + e], sl, slf) * sl;
    double pv = sum * (1.0 / S);
    pooled[(size_t)b*E + e] = pv;
    am = fabs(pv);
  }
  for(int m = 32; m > 0; m >>= 1) am = fmax(am, __shfl_xor(am, m));
  if((threadIdx.x & 63) == 0) atomic_max_d(slot_pooled, am);
}

__global__ void __launch_bounds__(64) cls_kernel(const double* __restrict__ pooled,
    const float* __restrict__ cw, const float* __restrict__ cb,
    float* __restrict__ out, const ull* __restrict__ sp,
    const ull* __restrict__ sw){
  int tid = blockIdx.x*64 + threadIdx.x;
  if(tid >= Bb*4) return;
  int b = tid >> 2, j = tid & 3;
  double s1 = slot_scale(sp), s2 = slot_scale(sw);
  float acc = 0.f;
  for(int e = 0; e < E; e++)
    acc += q_int_d(pooled[b*E + e], s1) * q_int_d((double)cw[j*E + e], s2);
  out[tid] = (float)((double)acc * (s1 * s2) + (double)cb[j]);
}

extern "C" void kernel_launch(void* const* d_in, const int* in_sizes, int n_in,
                              void* d_out, int out_size, void* d_ws, size_t ws_size,
                              hipStream_t stream){
  const float* x      = (const float*)d_in[0];
  const float* proj_w = (const float*)d_in[1];
  const float* proj_b = (const float*)d_in[2];
  const float* ln1_g  = (const float*)d_in[3];
  const float* ln1_b  = (const float*)d_in[4];
  const float* wq     = (const float*)d_in[5];
  const float* bq     = (const float*)d_in[6];
  const float* wk     = (const float*)d_in[7];
  const float* bk     = (const float*)d_in[8];
  const float* wv     = (const float*)d_in[9];
  const float* bv     = (const float*)d_in[10];
  const float* wo     = (const float*)d_in[11];
  const float* bo     = (const float*)d_in[12];
  const float* ln2_g  = (const float*)d_in[13];
  const float* ln2_b  = (const float*)d_in[14];
  const float* fc1_w  = (const float*)d_in[15];
  const float* fc1_b  = (const float*)d_in[16];
  const float* fc2_w  = (const float*)d_in[17];
  const float* fc2_b  = (const float*)d_in[18];
  const float* fn_g   = (const float*)d_in[19];
  const float* fn_b   = (const float*)d_in[20];
  const float* cls_w  = (const float*)d_in[21];
  const float* cls_b  = (const float*)d_in[22];
  float* outp = (float*)d_out;

  char* base = (char*)d_ws;
  ull*    slots  = (ull*)base;                                       // 4 KiB
  double* h      = (double*)(base + 4096);                           // 41.3 MB
  double* scr    = h + BUF;                                          // attn o / final LN
  float*  facc   = (float*)(scr + BUF);                              // arena (q/k/v accs)
  float*  qacc   = facc;
  double* pooled = (double*)facc;
  unsigned short* act8 = (unsigned short*)(facc + (size_t)M_TOK*MLPD);
  unsigned short* mid8 = act8 + (size_t)M_TOK*KP1;
  unsigned short* w8   = mid8 + (size_t)M_TOK*KP2;

  init_slots<<<1, 128, 0, stream>>>(slots);
  zero_pad<<<(M_TOK*2 + 255)/256, 256, 0, stream>>>(mid8);

  amax_f32<<<dim3(32,1), 256, 0, stream>>>(x,      Bb*CC*TT, slots + SLOT_X);
  amax_f32<<<dim3(1,1),  256, 0, stream>>>(proj_w, E*CC,     slots + SLOT_PW);
  amax_f32<<<dim3(1,1),  256, 0, stream>>>(cls_w,  4*E,      slots + SLOT_CW);
  amax_f32<<<dim3(4,NBLK),  256, 0, stream>>>(wq,    E*E,    slots + SLOT_WQ);
  amax_f32<<<dim3(4,NBLK),  256, 0, stream>>>(wk,    E*E,    slots + SLOT_WK);
  amax_f32<<<dim3(4,NBLK),  256, 0, stream>>>(wv,    E*E,    slots + SLOT_WV);
  amax_f32<<<dim3(4,NBLK),  256, 0, stream>>>(wo,    E*E,    slots + SLOT_WO);
  amax_f32<<<dim3(16,NBLK), 256, 0, stream>>>(fc1_w, MLPD*E, slots + SLOT_FC1);
  amax_f32<<<dim3(16,NBLK), 256, 0, stream>>>(fc2_w, MLPD*E, slots + SLOT_FC2);

  quant_w<<<dim3((KP1*KP1+255)/256, NBLK), 256, 0, stream>>>(wq, E, E, KP1, KP1, slots+SLOT_WQ, w8, WQ8_OFF);
  quant_w<<<dim3((KP1*KP1+255)/256, NBLK), 256, 0, stream>>>(wk, E, E, KP1, KP1, slots+SLOT_WK, w8, WK8_OFF);
  quant_w<<<dim3((KP1*KP1+255)/256, NBLK), 256, 0, stream>>>(wv, E, E, KP1, KP1, slots+SLOT_WV, w8, WV8_OFF);
  quant_w<<<dim3((KP1*KP1+255)/256, NBLK), 256, 0, stream>>>(wo, E, E, KP1, KP1, slots+SLOT_WO, w8, WO8_OFF);
  quant_w<<<dim3((MLPD*KP1+255)/256, NBLK), 256, 0, stream>>>(fc1_w, MLPD, E, MLPD, KP1, slots+SLOT_FC1, w8, FC18_OFF);
  quant_w<<<dim3((KP1*KP2+255)/256, NBLK), 256, 0, stream>>>(fc2_w, E, MLPD, KP1, KP2, slots+SLOT_FC2, w8, FC28_OFF);

  proj_bcast<<<(Bb*TT*E + 255)/256, 256, 0, stream>>>(x, proj_w, proj_b, h,
                                                      slots + SLOT_X, slots + SLOT_PW);

  const int QA_GRID = (M_TOK*KP1/8 + 255)/256;
  const int LN_GRID = 1792;

  // block-0 LN1 amax (later blocks get it fused into the fc2 epilogue)
  ln_amax<false><<<LN_GRID, 256, 0, stream>>>(h, nullptr, ln1_g, ln1_b, slots + SLOT_LN1);

  for(int i = 0; i < NBLK; i++){
    int pi = i & 1;
    const unsigned short* wb = w8 + (size_t)i*WBLK;
    // recompute LN1 + quantize (perm for odd blocks)
    if(pi == 0)
      ln_quant<0><<<LN_GRID, 256, 0, stream>>>(h, act8, ln1_g + i*E, ln1_b + i*E, slots + SLOT_LN1 + i);
    else
      ln_quant<1><<<LN_GRID, 256, 0, stream>>>(h, act8, ln1_g + i*E, ln1_b + i*E, slots + SLOT_LN1 + i);
    // fused QKV GEMMs
    gemm_qkv<<<dim3(3, M_TOK/64), 256, 0, stream>>>(act8, wb + WQ8_OFF, qacc);
    // attention -> scr (f64) + amax
    if(pi == 0){
      int nseg = (M_TOK/TT)*HH;
      attn_v2<TT><<<nseg/4, 64, 0, stream>>>(qacc, qacc + (size_t)M_TOK*E, qacc + (size_t)2*M_TOK*E, scr,
          bq + i*E, bk + i*E, bv + i*E,
          slots+SLOT_LN1+i, slots+SLOT_WQ+i, slots+SLOT_WK+i, slots+SLOT_WV+i,
          slots + SLOT_O + i);
    } else {
      int nseg = (M_TOK/CC)*HH;
      attn_v2<CC><<<nseg/4, 64, 0, stream>>>(qacc, qacc + (size_t)M_TOK*E, qacc + (size_t)2*M_TOK*E, scr,
          bq + i*E, bk + i*E, bv + i*E,
          slots+SLOT_LN1+i, slots+SLOT_WQ+i, slots+SLOT_WK+i, slots+SLOT_WV+i,
          slots + SLOT_O + i);
    }
    // quantize o -> act8
    quant_act<<<QA_GRID, 256, 0, stream>>>(scr, act8, slots + SLOT_O + i);
    // WO GEMM + residual + fused LN2 amax (paired-wave split)
    gemm_res_ln<6><<<M_TOK/64, 512, 0, stream>>>(act8, wb + WO8_OFF, bo + i*E,
        h, slots+SLOT_O+i, slots+SLOT_WO+i, slots+SLOT_LN2+i, pi,
        ln2_g + i*E, ln2_b + i*E);
    // recompute LN2 + quantize
    ln_quant<0><<<LN_GRID, 256, 0, stream>>>(h, act8, ln2_g + i*E, ln2_b + i*E, slots + SLOT_LN2 + i);
    // fc1 pass 1: gelu-amax candidates only (no store)
    gemm_mfma<6,9,2><<<dim3(5, M_TOK/64), 256, 0, stream>>>(act8, wb + FC18_OFF, fc1_b + i*MLPD, MLPD,
        nullptr, slots+SLOT_LN2+i, slots+SLOT_FC1+i, nullptr, slots + i);
    gelu_finalize<<<1, 64, 0, stream>>>(slots, i);
    // fc1 pass 2: fused gelu + quantize -> mid8 (bf16, coalesced via LDS)
    gemm_mfma<6,9,4><<<dim3(5, M_TOK/64), 256, 0, stream>>>(act8, wb + FC18_OFF, fc1_b + i*MLPD, MLPD,
        mid8, slots+SLOT_LN2+i, slots+SLOT_FC1+i, slots+SLOT_GELU+i, nullptr);
    // fc2 GEMM + residual + fused next-LN amax (paired-wave split)
    ull* nslot = (i < 5) ? (slots + SLOT_LN1 + i + 1) : (slots + SLOT_FLN);
    const float* ng = (i < 5) ? (ln1_g + (i+1)*E) : fn_g;
    const float* nb = (i < 5) ? (ln1_b + (i+1)*E) : fn_b;
    gemm_res_ln<23><<<M_TOK/64, 512, 0, stream>>>(mid8, wb + FC28_OFF, fc2_b + i*E,
        h, slots+SLOT_GELU+i, slots+SLOT_FC2+i, nslot, 0, ng, nb);
  }

  // final LN writes rows for pooling (amax already fused; extra atomicMax harmless)
  ln_amax<true><<<LN_GRID, 256, 0, stream>>>(h, scr, fn_g, fn_b, slots + SLOT_FLN);
  pooled_kernel<<<(Bb*E + 255)/256, 256, 0, stream>>>(scr, pooled, slots + SLOT_FLN, slots + SLOT_POOL);
  cls_kernel<<<(Bb*4 + 63)/64, 64, 0, stream>>>(pooled, cls_w, cls_b, outp,
                                                slots + SLOT_POOL, slots + SLOT_CW);
}